// Round 8
// baseline (58.387 us; speedup 1.0000x reference)
//
#include <hip/hip_runtime.h>

// B=256, IN_F=512, K_INT=75, OUT_F=64
// ws: Mt[o][k][b] fp32    @ 0          (4,915,200 B)
//     Tb[k*64+o][f] bf16  @ 4,915,200  (4,915,200 B)
//     xb[b][f] bf16       @ 9,830,400  (  262,144 B)

typedef __attribute__((ext_vector_type(8))) short bf16x8;
typedef __attribute__((ext_vector_type(4))) float f32x4;
typedef unsigned short u16;
typedef unsigned int u32;

__device__ inline u16 f2bf(float f) {            // RNE float->bf16 bits
  u32 u = __float_as_uint(f);
  return (u16)((u + 0x7FFFu + ((u >> 16) & 1u)) >> 16);
}

// ---------- fused convert: blocks 0..599 = T-transpose tiles, 600..663 = x chunks ----------
__global__ __launch_bounds__(256) void cvt_all(const float* __restrict__ x,
                                               const float* __restrict__ T,
                                               u16* __restrict__ xb,
                                               u16* __restrict__ Tb) {
  const int bid = blockIdx.x;
  const int tid = threadIdx.x;

  if (bid >= 600) {                  // ---- x[256][512] fp32 -> xb[b][f] bf16
    const int i = (bid - 600) * 256 + tid;
    const float4* x4 = reinterpret_cast<const float4*>(x);
    const float4 v0 = x4[i * 2], v1 = x4[i * 2 + 1];
    uint4 o;
    o.x = (u32)f2bf(v0.x) | ((u32)f2bf(v0.y) << 16);
    o.y = (u32)f2bf(v0.z) | ((u32)f2bf(v0.w) << 16);
    o.z = (u32)f2bf(v1.x) | ((u32)f2bf(v1.y) << 16);
    o.w = (u32)f2bf(v1.z) | ((u32)f2bf(v1.w) << 16);
    *reinterpret_cast<uint4*>(xb + i * 8) = o;
    return;
  }

  // ---- T[f][k][o] fp32 -> Tb[k*64+o][f] bf16 (64x64 LDS transpose, verbatim R5)
  const int f0 = (bid & 7) << 6;
  const int k = bid >> 3;            // 0..74
  __shared__ float tile[64][65];

  const float4* T4 = reinterpret_cast<const float4*>(T);
  const int r = tid >> 2;
  const int c = tid & 3;
#pragma unroll
  for (int h = 0; h < 4; ++h) {
    const int q = c + (h << 2);
    const float4 v = T4[(f0 + r) * 1200 + k * 16 + q];
    tile[r][(q << 2) + 0] = v.x;
    tile[r][(q << 2) + 1] = v.y;
    tile[r][(q << 2) + 2] = v.z;
    tile[r][(q << 2) + 3] = v.w;
  }
  __syncthreads();

  const int w = tid >> 2;
  u16 us[16];
#pragma unroll
  for (int j = 0; j < 16; ++j) us[j] = f2bf(tile[(c << 4) + j][w]);
  uint4 p0, p1;
  p0.x = (u32)us[0] | ((u32)us[1] << 16);
  p0.y = (u32)us[2] | ((u32)us[3] << 16);
  p0.z = (u32)us[4] | ((u32)us[5] << 16);
  p0.w = (u32)us[6] | ((u32)us[7] << 16);
  p1.x = (u32)us[8] | ((u32)us[9] << 16);
  p1.y = (u32)us[10] | ((u32)us[11] << 16);
  p1.z = (u32)us[12] | ((u32)us[13] << 16);
  p1.w = (u32)us[14] | ((u32)us[15] << 16);
  uint4* dst = reinterpret_cast<uint4*>(Tb + ((k << 6) + w) * 512 + f0 + (c << 4));
  dst[0] = p0;
  dst[1] = p1;
}

// ---------- MFMA GEMM (verbatim R5): Mt[o][k][b] = sum_f Tb[k*64+o][f]*xb[b][f] ----------
__global__ __launch_bounds__(256) void md_gemm_mfma(const u16* __restrict__ Tb,
                                                    const u16* __restrict__ xb,
                                                    float* __restrict__ Mt) {
  const int tid = threadIdx.x;
  const int l = tid & 63, w = tid >> 6;
  const int n0 = (blockIdx.x << 6) + ((w >> 1) << 5);
  const int b0 = (blockIdx.y << 6) + ((w & 1) << 5);
  const int lr = l & 15;
  const int ko = (l >> 4) << 3;

  const u16* pa0 = Tb + (n0 + lr) * 512 + ko;
  const u16* pa1 = pa0 + 16 * 512;
  const u16* pb0 = xb + (b0 + lr) * 512 + ko;
  const u16* pb1 = pb0 + 16 * 512;

  f32x4 d00 = {0.f, 0.f, 0.f, 0.f}, d01 = d00, d10 = d00, d11 = d00;

#pragma unroll 4
  for (int kk = 0; kk < 16; ++kk) {
    const int off = kk << 5;
    const bf16x8 a0 = *reinterpret_cast<const bf16x8*>(pa0 + off);
    const bf16x8 a1 = *reinterpret_cast<const bf16x8*>(pa1 + off);
    const bf16x8 f0 = *reinterpret_cast<const bf16x8*>(pb0 + off);
    const bf16x8 f1 = *reinterpret_cast<const bf16x8*>(pb1 + off);
    d00 = __builtin_amdgcn_mfma_f32_16x16x32_bf16(a0, f0, d00, 0, 0, 0);
    d01 = __builtin_amdgcn_mfma_f32_16x16x32_bf16(a0, f1, d01, 0, 0, 0);
    d10 = __builtin_amdgcn_mfma_f32_16x16x32_bf16(a1, f0, d10, 0, 0, 0);
    d11 = __builtin_amdgcn_mfma_f32_16x16x32_bf16(a1, f1, d11, 0, 0, 0);
  }

#pragma unroll
  for (int r = 0; r < 4; ++r) {
    const int row = ((l >> 4) << 2) + r;
    {
      const int n = n0 + row;
      float* base = Mt + (n & 63) * 19200 + (n >> 6) * 256;
      base[b0 + lr] = d00[r];
      base[b0 + 16 + lr] = d01[r];
    }
    {
      const int n = n0 + 16 + row;
      float* base = Mt + (n & 63) * 19200 + (n >> 6) * 256;
      base[b0 + lr] = d10[r];
      base[b0 + 16 + lr] = d11[r];
    }
  }
}

// ---------- pairwise: block = (o, 64-i tile), 8i x 8j per thread, full j-range ----------
// Grid 256 (bid&63 = o -> same-o blocks on same XCD). LDS = full M_o (76.8 KB), 1 block/CU.
// Per CU per k: LDS 4w*4*12=192 cyc < VALU 4w*128*2/4=256 cyc -> VALU-bound.
__global__ __launch_bounds__(256, 1) void md_pair2(const float* __restrict__ Mt,
                                                   float* __restrict__ out) {
  const int bid = blockIdx.x;
  const int o = bid & 63;
  const int ibase = (bid >> 6) << 6;   // i-tile base: 0/64/128/192
  const int tid = threadIdx.x;

  __shared__ alignas(16) float Ms[75 * 256];   // 76,800 B

  // stage full M_o: 4800 float4, coalesced global (L2-hot), conflict-free LDS
  {
    const float4* src = reinterpret_cast<const float4*>(Mt + o * 19200);
    float4* dst = reinterpret_cast<float4*>(Ms);
    for (int t = tid; t < 4800; t += 256) dst[t] = src[t];
  }
  __syncthreads();

  const int is = tid & 7;              // i = ibase + 8*is + a
  const int js = tid >> 3;             // j = 8*js + b   (js 0..31)
  const int ifq = ((ibase >> 2) + (is << 1));  // float4 index of own i-octet

  float d[8][8];
#pragma unroll
  for (int a = 0; a < 8; ++a)
#pragma unroll
    for (int b = 0; b < 8; ++b) d[a][b] = 0.0f;

#pragma unroll 2
  for (int k = 0; k < 75; ++k) {
    const float4* row4 = reinterpret_cast<const float4*>(Ms + (k << 8));
    const float4 vi0 = row4[ifq];            // all reads <=2-way bank-aliased: free
    const float4 vi1 = row4[ifq + 1];
    const float4 vj0 = row4[(js << 1)];
    const float4 vj1 = row4[(js << 1) + 1];
    const float ia[8] = {vi0.x, vi0.y, vi0.z, vi0.w, vi1.x, vi1.y, vi1.z, vi1.w};
    const float ja[8] = {vj0.x, vj0.y, vj0.z, vj0.w, vj1.x, vj1.y, vj1.z, vj1.w};
#pragma unroll
    for (int a = 0; a < 8; ++a)
#pragma unroll
      for (int b = 0; b < 8; ++b) d[a][b] += __builtin_fabsf(ja[b] - ia[a]);
  }

  float isum[8];
#pragma unroll
  for (int a = 0; a < 8; ++a) {
    float s = 0.0f;
#pragma unroll
    for (int b = 0; b < 8; ++b) s += __expf(-d[a][b]);  // j==i: exp(0)=1, cancelled by -1
    isum[a] = s;
  }

  // reduce over the 8 j-slots within each wave (lane bits 3..5) via xor-butterfly
#pragma unroll
  for (int m = 8; m <= 32; m <<= 1)
#pragma unroll
    for (int a = 0; a < 8; ++a) isum[a] += __shfl_xor(isum[a], m);

  __syncthreads();                     // Ms reads done; overlay reduce scratch
  float* red = Ms;                     // red[wave][72]
  const int wv = tid >> 6;
  if (((tid >> 3) & 7) == 0) {         // one lane-octet per wave holds the sums
#pragma unroll
    for (int a = 0; a < 8; ++a) red[wv * 72 + (is << 3) + a] = isum[a];
  }
  __syncthreads();
  if (tid < 64) {
    const float s = red[tid] + red[72 + tid] + red[144 + tid] + red[216 + tid];
    out[(ibase + tid) * 64 + o] = s - 1.0f;
  }
}

extern "C" void kernel_launch(void* const* d_in, const int* in_sizes, int n_in,
                              void* d_out, int out_size, void* d_ws, size_t ws_size,
                              hipStream_t stream) {
  const float* x = (const float*)d_in[0];   // [256,512]
  const float* T = (const float*)d_in[1];   // [512,75,64]
  float* out = (float*)d_out;               // [256,64]

  char* ws = (char*)d_ws;
  float* Mt = (float*)ws;                   // 4,915,200 B
  u16* Tb = (u16*)(ws + 4915200);           // 4,915,200 B
  u16* xb = (u16*)(ws + 9830400);           //   262,144 B

  cvt_all<<<664, 256, 0, stream>>>(x, T, xb, Tb);
  md_gemm_mfma<<<dim3(75, 4), 256, 0, stream>>>(Tb, xb, Mt);
  md_pair2<<<256, 256, 0, stream>>>(Mt, out);
}